// Round 9
// baseline (194.532 us; speedup 1.0000x reference)
//
#include <hip/hip_runtime.h>
#include <hip/hip_bf16.h>
#include <math.h>

#define NTOK 65536
#define DIM  128
#define NE   9
#define TOPK 3
#define ALPHA_C 1e-4f

using bf16x8 = __attribute__((ext_vector_type(8))) short;
using f32x4  = __attribute__((ext_vector_type(4))) float;

// ws layout (bytes)
static constexpr size_t OFF_MG   = 0;        // 32 f32
static constexpr size_t OFF_CNT  = 128;      // 9 u32
static constexpr size_t OFF_GSUM = 192;      // 9 f32
static constexpr size_t OFF_SB   = 256;      // 9*128 f32 -> 4864
static constexpr size_t OFF_W1F  = 4864;     // 9*128*128 bf16 (frag-ordered) -> 299776
static constexpr size_t OFF_W2F  = 299776;   // -> 594688

__device__ __forceinline__ unsigned short f2bf(float f) {
    __hip_bfloat16 h = __float2bfloat16(f);
    return *reinterpret_cast<unsigned short*>(&h);
}

// ---------------- K_prep: fused {market(256) | prepw(72) | stylebias(9)} by block range
// market: one token per thread; weights via wave-uniform s_load (SMEM pipe),
// x via LDS (stride 132 pad). 4096 FMA/thread = VALU floor.
__global__ __launch_bounds__(256) void k_prep(const float* __restrict__ x,
    const float* __restrict__ Wrw, const float* __restrict__ Wrb,
    const float* __restrict__ Wlw, float* __restrict__ mg_acc,
    const float* __restrict__ W1, const float* __restrict__ W2,
    unsigned short* __restrict__ W1F, unsigned short* __restrict__ W2F,
    const float* __restrict__ styles, const float* __restrict__ b1,
    float* __restrict__ sb)
{
    __shared__ float xs[256 * 132];   // 135168 B
    __shared__ float wpart[4][32];
    int bid = blockIdx.x;
    int tid = threadIdx.x;

    if (bid < 256) {
        // ---- market: market = relu(x@Wr+b); mg[m] += sum market[n][m]*wl[n]
        int base = bid * 256;
        const float4* x4g = (const float4*)x + (size_t)base * 32;
        for (int i = tid; i < 256 * 32; i += 256) {
            int row = i >> 5, c = i & 31;
            *(float4*)(xs + row * 132 + c * 4) = x4g[i];
        }
        __syncthreads();

        float acc[32];
        #pragma unroll
        for (int m = 0; m < 32; ++m) acc[m] = 0.f;

        const float* xrow = xs + tid * 132;
        for (int c = 0; c < 32; ++c) {
            float4 xv = *(const float4*)(xrow + c * 4);
            float xa[4] = {xv.x, xv.y, xv.z, xv.w};
            #pragma unroll
            for (int dd = 0; dd < 4; ++dd) {
                int d = c * 4 + dd;
                #pragma unroll
                for (int mq = 0; mq < 8; ++mq) {
                    // uniform address -> scalar loads, FMA with SGPR operand
                    float4 wv = *(const float4*)(Wrw + d * 32 + mq * 4);
                    acc[mq * 4 + 0] += xa[dd] * wv.x;
                    acc[mq * 4 + 1] += xa[dd] * wv.y;
                    acc[mq * 4 + 2] += xa[dd] * wv.z;
                    acc[mq * 4 + 3] += xa[dd] * wv.w;
                }
            }
        }

        float wl = Wlw[base + tid];
        #pragma unroll
        for (int mq = 0; mq < 8; ++mq) {
            float4 bv = *(const float4*)(Wrb + mq * 4);   // uniform
            float ba[4] = {bv.x, bv.y, bv.z, bv.w};
            #pragma unroll
            for (int j = 0; j < 4; ++j) {
                float v = acc[mq * 4 + j] + ba[j];
                acc[mq * 4 + j] = (v > 0.f ? v : 0.f) * wl;
            }
        }
        // reduce over 64 lanes (tokens)
        #pragma unroll
        for (int off = 1; off <= 32; off <<= 1)
            #pragma unroll
            for (int m = 0; m < 32; ++m)
                acc[m] += __shfl_xor(acc[m], off);
        int lane = tid & 63, wv_ = tid >> 6;
        if (lane == 0)
            #pragma unroll
            for (int m = 0; m < 32; ++m) wpart[wv_][m] = acc[m];
        __syncthreads();
        if (tid < 32) {
            float s = wpart[0][tid] + wpart[1][tid] + wpart[2][tid] + wpart[3][tid];
            atomicAdd(&mg_acc[tid], s);
        }
    } else if (bid < 328) {
        // ---- prepw: frag-ordered bf16 weights
        // WF[e][mt][kk][lane][j] = W[e][kk*32+(lane>>4)*8+j][mt*16+(lane&15)]
        int b = bid - 256;
        int e = b >> 3, n = b & 7;
        int kk = tid >> 6, l = tid & 63;
        int row0 = kk * 32 + (l >> 4) * 8;
        int col  = n * 16 + (l & 15);
        const float* W1e = W1 + (size_t)e * 20480;   // [160][128]
        const float* W2e = W2 + (size_t)e * 16384;   // [128][128]
        size_t ob = (size_t)e * 16384 + n * 2048 + kk * 512 + l * 8;
        unsigned short u1[8], u2[8];
        #pragma unroll
        for (int j = 0; j < 8; ++j) {
            u1[j] = f2bf(W1e[(size_t)(row0 + j) * 128 + col]);
            u2[j] = f2bf(W2e[(size_t)(row0 + j) * 128 + col]);
        }
        *(ushort4*)(W1F + ob)     = *(ushort4*)(u1);
        *(ushort4*)(W1F + ob + 4) = *(ushort4*)(u1 + 4);
        *(ushort4*)(W2F + ob)     = *(ushort4*)(u2);
        *(ushort4*)(W2F + ob + 4) = *(ushort4*)(u2 + 4);
    } else {
        // ---- stylebias
        int e = bid - 328;
        if (tid < 128) {
            int h = tid;
            float acc = b1[e * 128 + h];
            for (int s = 0; s < 32; ++s)
                acc += styles[e * 32 + s] * W1[(size_t)e * 20480 + (size_t)(128 + s) * 128 + h];
            sb[e * 128 + h] = acc;
        }
    }
}

// ---------------- K3: aux loss scalar
__global__ void k_aux(const unsigned* __restrict__ cnt, const float* __restrict__ gsum,
                      float* __restrict__ out)
{
    float a = 0.f;
    for (int e = 0; e < 9; ++e) {
        float fi = (float)cnt[e] * ((float)NE / ((float)TOPK * (float)NTOK));
        float Pi = gsum[e] / (float)NTOK;
        a += fi * Pi;
    }
    out[(size_t)NTOK * DIM] = ALPHA_C * a;
}

// ---------------- K_fused: router + dense 9-expert FFN, transposed GEMM space.
// H^T = W1x^T @ X^T, O^T = W2^T @ H^T. A = frag-ordered W (global, coalesced),
// B = swizzled LDS xs/hs. A1-frags prefetched one expert ahead (latency lands
// in the barrier drain, not phase-1 start). setprio(1) around MFMA clusters.
__global__ __launch_bounds__(256) void k_fused(const float* __restrict__ x,
    const float* __restrict__ rweights, const float* __restrict__ rb,
    const float* __restrict__ mg, const float* __restrict__ Wlb,
    const unsigned short* __restrict__ W1F, const unsigned short* __restrict__ W2F,
    const float* __restrict__ sbg, const float* __restrict__ b2g,
    unsigned* __restrict__ cnt, float* __restrict__ gsum,
    float* __restrict__ out)
{
    __shared__ unsigned short xs[64 * 128];   // 16 KB swizzled bf16 X
    __shared__ unsigned short hs[64 * 128];   // 16 KB swizzled bf16 H; router overlay
    __shared__ float garr[64][12];
    __shared__ float ce[9];
    __shared__ unsigned lcount[9];
    __shared__ float lgsum[9];

    float* part = (float*)hs;                 // [64][4][9] f32
    float* rwp  = (float*)hs + 2304;          // 160*9 f32 -> 14976 B < 16 KB

    int tid = threadIdx.x;
    int base = blockIdx.x * 64;

    for (int i = tid; i < 160 * 9; i += 256) rwp[i] = rweights[i];
    if (tid < 9) { lcount[tid] = 0u; lgsum[tid] = 0.f; }
    __syncthreads();

    // router partials: 4 threads/token, d-interleaved (bank-clean)
    int tok = tid >> 2, sub = tid & 3;
    {
        float acc[9];
        #pragma unroll
        for (int e = 0; e < 9; ++e) acc[e] = 0.f;
        const float* xrow = x + (size_t)(base + tok) * 128 + sub;
        for (int d = 0; d < 32; ++d) {
            float xv = xrow[d * 4];
            #pragma unroll
            for (int e = 0; e < 9; ++e) acc[e] += xv * rwp[(d * 4 + sub) * 9 + e];
        }
        #pragma unroll
        for (int e = 0; e < 9; ++e) part[(tok * 4 + sub) * 9 + e] = acc[e];
    }
    if (tid < 9) {
        float c = rb[tid];
        float wlb = Wlb[0];
        for (int m = 0; m < 32; ++m) c += (mg[m] + wlb) * rwp[(128 + m) * 9 + tid];
        ce[tid] = c;
    }
    // stage X -> swizzled bf16 LDS
    {
        const float4* x4 = (const float4*)x;
        for (int i = tid; i < 64 * 32; i += 256) {
            int row = i >> 5, p = i & 31;
            float4 v = x4[(size_t)(base + row) * 32 + p];
            unsigned short u[4] = { f2bf(v.x), f2bf(v.y), f2bf(v.z), f2bf(v.w) };
            int sw = ((((p >> 1) ^ (row & 7)) << 4) | ((p & 1) << 3));
            *(ushort4*)((char*)xs + row * 256 + sw) = *(ushort4*)u;
        }
    }
    __syncthreads();

    if (sub == 0) {
        float lg[9];
        #pragma unroll
        for (int e = 0; e < 9; ++e)
            lg[e] = ce[e] + part[(tok * 4 + 0) * 9 + e] + part[(tok * 4 + 1) * 9 + e]
                  + part[(tok * 4 + 2) * 9 + e] + part[(tok * 4 + 3) * 9 + e];
        int used = 0;
        int bi[3]; float bv[3];
        for (int k = 0; k < 3; ++k) {
            float best = -1e30f; int b = -1;
            for (int e = 0; e < 9; ++e)
                if (!((used >> e) & 1) && lg[e] > best) { best = lg[e]; b = e; }
            bi[k] = b; bv[k] = best; used |= 1 << b;
        }
        float p3[3]; float s = 0.f;
        for (int k = 0; k < 3; ++k) { p3[k] = expf(bv[k] - bv[0]); s += p3[k]; }
        #pragma unroll
        for (int e = 0; e < 12; ++e) garr[tok][e] = 0.f;
        for (int k = 0; k < 3; ++k) {
            float g = p3[k] / s;
            garr[tok][bi[k]] = g;
            atomicAdd(&lcount[bi[k]], 1u);
            atomicAdd(&lgsum[bi[k]], g);
        }
    }
    __syncthreads();   // garr ready; hs (part/rwp) free
    if (tid < 9) {
        atomicAdd(&cnt[tid], lcount[tid]);
        atomicAdd(&gsum[tid], lgsum[tid]);
    }

    int lane = tid & 63, w = tid >> 6;
    int tl = lane & 15;     // token-within-Ntile
    int hq = lane >> 4;     // quarter
    int xr = tl & 7;        // swizzle xor term

    f32x4 acc_out[2][4];
    #pragma unroll
    for (int mi = 0; mi < 2; ++mi)
        #pragma unroll
        for (int ni = 0; ni < 4; ++ni) acc_out[mi][ni] = (f32x4){0.f, 0.f, 0.f, 0.f};

    const unsigned short* A1b = W1F + (w * 2) * 2048 + lane * 8;
    const unsigned short* A2b = W2F + (w * 2) * 2048 + lane * 8;

    // prefetch A1 for e=0
    bf16x8 a1c[2][4];
    #pragma unroll
    for (int mi = 0; mi < 2; ++mi)
        #pragma unroll
        for (int kk = 0; kk < 4; ++kk)
            a1c[mi][kk] = *(const bf16x8*)(A1b + mi * 2048 + kk * 512);

    #pragma unroll 1
    for (int e = 0; e < 9; ++e) {
        float4 sbv0 = *(const float4*)(sbg + e * 128 + (w * 2 + 0) * 16 + hq * 4);
        float4 sbv1 = *(const float4*)(sbg + e * 128 + (w * 2 + 1) * 16 + hq * 4);
        f32x4 acc1[2][4];
        #pragma unroll
        for (int ni = 0; ni < 4; ++ni) {
            acc1[0][ni] = (f32x4){sbv0.x, sbv0.y, sbv0.z, sbv0.w};
            acc1[1][ni] = (f32x4){sbv1.x, sbv1.y, sbv1.z, sbv1.w};
        }

        // Phase 1: H^T = W1x^T @ X^T (+sb)
        __builtin_amdgcn_s_setprio(1);
        #pragma unroll
        for (int kk = 0; kk < 4; ++kk) {
            #pragma unroll
            for (int ni = 0; ni < 4; ++ni) {
                bf16x8 b = *(const bf16x8*)((const char*)xs + (ni * 16 + tl) * 256
                               + ((((kk * 4 + hq) ^ xr) << 4)));
                acc1[0][ni] = __builtin_amdgcn_mfma_f32_16x16x32_bf16(a1c[0][kk], b, acc1[0][ni], 0, 0, 0);
                acc1[1][ni] = __builtin_amdgcn_mfma_f32_16x16x32_bf16(a1c[1][kk], b, acc1[1][ni], 0, 0, 0);
            }
        }
        __builtin_amdgcn_s_setprio(0);

        // A2 loads issued now: latency hides under epilogue
        bf16x8 a2[2][4];
        #pragma unroll
        for (int mi = 0; mi < 2; ++mi)
            #pragma unroll
            for (int kk = 0; kk < 4; ++kk)
                a2[mi][kk] = *(const bf16x8*)(A2b + (size_t)e * 16384 + mi * 2048 + kk * 512);

        // Epilogue 1: H = relu(acc1)*g -> hs (swizzled, b64 writes)
        #pragma unroll
        for (int ni = 0; ni < 4; ++ni) {
            int t = ni * 16 + tl;
            float g = garr[t][e];
            char* rowp = (char*)hs + t * 256;
            #pragma unroll
            for (int mi = 0; mi < 2; ++mi) {
                f32x4 v = acc1[mi][ni];
                unsigned short u[4];
                u[0] = f2bf(fmaxf(v[0], 0.f) * g);
                u[1] = f2bf(fmaxf(v[1], 0.f) * g);
                u[2] = f2bf(fmaxf(v[2], 0.f) * g);
                u[3] = f2bf(fmaxf(v[3], 0.f) * g);
                int chunk = (w * 2 + mi) * 2 + (hq >> 1);
                int off = (hq & 1) * 8;
                *(ushort4*)(rowp + (((chunk ^ xr) << 4) | off)) = *(ushort4*)u;
            }
        }
        // prefetch A1 for e+1: completes during the barrier drain
        if (e != 8) {
            #pragma unroll
            for (int mi = 0; mi < 2; ++mi)
                #pragma unroll
                for (int kk = 0; kk < 4; ++kk)
                    a1c[mi][kk] = *(const bf16x8*)(A1b + (size_t)(e + 1) * 16384 + mi * 2048 + kk * 512);
        }
        __syncthreads();   // hs complete

        // Phase 2: O^T += W2^T @ H^T
        __builtin_amdgcn_s_setprio(1);
        #pragma unroll
        for (int kk = 0; kk < 4; ++kk) {
            #pragma unroll
            for (int ni = 0; ni < 4; ++ni) {
                bf16x8 b = *(const bf16x8*)((const char*)hs + (ni * 16 + tl) * 256
                               + ((((kk * 4 + hq) ^ xr) << 4)));
                acc_out[0][ni] = __builtin_amdgcn_mfma_f32_16x16x32_bf16(a2[0][kk], b, acc_out[0][ni], 0, 0, 0);
                acc_out[1][ni] = __builtin_amdgcn_mfma_f32_16x16x32_bf16(a2[1][kk], b, acc_out[1][ni], 0, 0, 0);
            }
        }
        __builtin_amdgcn_s_setprio(0);
        if (e != 8) __syncthreads();   // hs consumed before next epilogue overwrites
    }

    // Final: out[t][d] = acc_out + sum_e g[t][e]*b2[e][d]
    #pragma unroll
    for (int mi = 0; mi < 2; ++mi) {
        int d0 = (w * 2 + mi) * 16 + hq * 4;
        float4 b2v[9];
        #pragma unroll
        for (int e = 0; e < 9; ++e) b2v[e] = *(const float4*)(b2g + e * 128 + d0);
        #pragma unroll
        for (int ni = 0; ni < 4; ++ni) {
            int t = ni * 16 + tl;
            float4 bias = {0.f, 0.f, 0.f, 0.f};
            #pragma unroll
            for (int e = 0; e < 9; ++e) {
                float g = garr[t][e];
                bias.x += g * b2v[e].x; bias.y += g * b2v[e].y;
                bias.z += g * b2v[e].z; bias.w += g * b2v[e].w;
            }
            f32x4 v = acc_out[mi][ni];
            float4 r = {v[0] + bias.x, v[1] + bias.y, v[2] + bias.z, v[3] + bias.w};
            *(float4*)(out + (size_t)(base + t) * 128 + d0) = r;
        }
    }
}

extern "C" void kernel_launch(void* const* d_in, const int* in_sizes, int n_in,
                              void* d_out, int out_size, void* d_ws, size_t ws_size,
                              hipStream_t stream) {
    const float* x      = (const float*)d_in[0];
    const float* Wrw    = (const float*)d_in[1];
    const float* Wrb    = (const float*)d_in[2];
    const float* Wlw    = (const float*)d_in[3];
    const float* Wlb    = (const float*)d_in[4];
    const float* rw     = (const float*)d_in[5];
    const float* rb     = (const float*)d_in[6];
    const float* styles = (const float*)d_in[7];
    const float* W1     = (const float*)d_in[8];
    const float* b1     = (const float*)d_in[9];
    const float* W2     = (const float*)d_in[10];
    const float* b2     = (const float*)d_in[11];
    float* out = (float*)d_out;

    char* ws = (char*)d_ws;
    float*          mg    = (float*)(ws + OFF_MG);
    unsigned*       cnt   = (unsigned*)(ws + OFF_CNT);
    float*          gsum  = (float*)(ws + OFF_GSUM);
    float*          sbp   = (float*)(ws + OFF_SB);
    unsigned short* W1F   = (unsigned short*)(ws + OFF_W1F);
    unsigned short* W2F   = (unsigned short*)(ws + OFF_W2F);

    hipMemsetAsync(ws, 0, 256, stream);   // mg, cnt, gsum

    k_prep<<<337, 256, 0, stream>>>(x, Wrw, Wrb, Wlw, mg, W1, W2, W1F, W2F,
                                    styles, b1, sbp);
    k_fused<<<1024, 256, 0, stream>>>(x, rw, rb, mg, Wlb, W1F, W2F, sbp, b2,
                                      cnt, gsum, out);
    k_aux<<<1, 1, 0, stream>>>(cnt, gsum, out);
}